// Round 7
// baseline (25.864 us; speedup 1.0000x reference)
//
#include <hip/hip_runtime.h>

// MedianPool: x (32, 4096, 128) f32, window=5, circular pad along dim 1,
// lower median (sorted[2] of 5). Output f32 same shape.
//
// R6: LDS-staged block tiling. Block = 64 output rows of one batch; stage 68
// input rows (34 KB LDS) once -> HBM amplification 1.06x (was 1.5x).
// 7-op median-of-5 via v_med3_f32, XCD swizzle, nontemporal stores.

constexpr int B   = 32;
constexpr int L   = 4096;    // power of two -> wrap via mask
constexpr int C   = 128;
constexpr int C4  = C / 4;   // f32x4 per row = 32
constexpr int BR  = 64;      // output rows per block
constexpr int SR  = BR + 4;  // staged input rows = 68
constexpr int RPT = 8;       // output rows per thread (256 thr = 8 subgroups x 32 c4)
constexpr int NXCD = 8;

typedef float f32x4 __attribute__((ext_vector_type(4)));

__device__ __forceinline__ f32x4 f4min(f32x4 a, f32x4 b) {
    f32x4 r;
    r.x = fminf(a.x, b.x); r.y = fminf(a.y, b.y);
    r.z = fminf(a.z, b.z); r.w = fminf(a.w, b.w);
    return r;
}
__device__ __forceinline__ f32x4 f4max(f32x4 a, f32x4 b) {
    f32x4 r;
    r.x = fmaxf(a.x, b.x); r.y = fmaxf(a.y, b.y);
    r.z = fmaxf(a.z, b.z); r.w = fmaxf(a.w, b.w);
    return r;
}
__device__ __forceinline__ f32x4 f4med3(f32x4 a, f32x4 b, f32x4 c) {
    f32x4 r;
    r.x = __builtin_amdgcn_fmed3f(a.x, b.x, c.x);
    r.y = __builtin_amdgcn_fmed3f(a.y, b.y, c.y);
    r.z = __builtin_amdgcn_fmed3f(a.z, b.z, c.z);
    r.w = __builtin_amdgcn_fmed3f(a.w, b.w, c.w);
    return r;
}

// Lower median of 5, 7 ops.
__device__ __forceinline__ f32x4 median5(f32x4 a, f32x4 b, f32x4 c,
                                         f32x4 d, f32x4 e) {
    f32x4 t1 = f4min(a, b), t2 = f4max(a, b);
    f32x4 t3 = f4min(c, d), t4 = f4max(c, d);
    f32x4 t5 = f4max(t1, t3);
    f32x4 t6 = f4min(t2, t4);
    return f4med3(t5, t6, e);
}

__global__ __launch_bounds__(256)
void MedianPool_73426760893099_kernel(const f32x4* __restrict__ x,
                                      f32x4* __restrict__ out) {
    __shared__ f32x4 smem[SR * C4];   // 68 * 32 * 16 B = 34816 B

    // XCD-contiguous swizzle: nwg = 2048, divisible by 8.
    const int nwg  = gridDim.x;
    const int cpx  = nwg / NXCD;
    const int bid  = (int)blockIdx.x;
    const int bsw  = (bid % NXCD) * cpx + bid / NXCD;

    const int b  = bsw >> 6;          // bsw / (L/BR) ; L/BR = 64
    const int l0 = (bsw & 63) * BR;

    const int tid = threadIdx.x;
    const f32x4* __restrict__ xb = x + (size_t)b * L * C4;

    // Cooperative stage: 68 rows x 32 f32x4 = 2176 elements, 16 B/lane coalesced.
#pragma unroll
    for (int j = tid; j < SR * C4; j += 256) {
        const int r = j >> 5;         // staged row
        const int c = j & (C4 - 1);
        smem[j] = xb[(size_t)((l0 + r) & (L - 1)) * C4 + c];
    }
    __syncthreads();

    const int sub  = tid >> 5;        // 0..7
    const int c4   = tid & (C4 - 1);
    const int base = sub * RPT;       // first output row (block-relative)

    // Read the 12 LDS rows this thread needs (2-way bank aliasing max = free).
    f32x4 r[RPT + 4];
#pragma unroll
    for (int i = 0; i < RPT + 4; ++i)
        r[i] = smem[(base + i) * C4 + c4];

    f32x4* o = out + ((size_t)b * L + l0 + base) * C4 + c4;
#pragma unroll
    for (int i = 0; i < RPT; ++i) {
        f32x4 m = median5(r[i], r[i + 1], r[i + 2], r[i + 3], r[i + 4]);
        __builtin_nontemporal_store(m, o + i * C4);
    }
}

extern "C" void kernel_launch(void* const* d_in, const int* in_sizes, int n_in,
                              void* d_out, int out_size, void* d_ws, size_t ws_size,
                              hipStream_t stream) {
    const f32x4* x   = (const f32x4*)d_in[0];
    f32x4*       out = (f32x4*)d_out;

    const int grid = B * (L / BR);    // 32 * 64 = 2048 blocks
    MedianPool_73426760893099_kernel<<<grid, 256, 0, stream>>>(x, out);
}

// Round 8
// 24.253 us; speedup vs baseline: 1.0664x; 1.0664x over previous
//
#include <hip/hip_runtime.h>

// MedianPool: x (32, 4096, 128) f32, window=5, circular pad along dim 1,
// lower median (sorted[2] of 5). Output f32 same shape.
//
// R7: R3 structure (RPT=8, 12 row loads -> 8 medians, 7-op median-of-5 via
// v_med3_f32, XCD-contiguous swizzle) with PLAIN stores (A/B vs nontemporal).

constexpr int B   = 32;
constexpr int L   = 4096;    // power of two -> wrap via mask
constexpr int C   = 128;
constexpr int C4  = C / 4;   // f32x4 per row = 32
constexpr int RPT = 8;       // output rows per thread
constexpr int LG  = L / RPT; // 512 row-groups per batch
constexpr int NXCD = 8;

typedef float f32x4 __attribute__((ext_vector_type(4)));

__device__ __forceinline__ f32x4 f4min(f32x4 a, f32x4 b) {
    f32x4 r;
    r.x = fminf(a.x, b.x); r.y = fminf(a.y, b.y);
    r.z = fminf(a.z, b.z); r.w = fminf(a.w, b.w);
    return r;
}
__device__ __forceinline__ f32x4 f4max(f32x4 a, f32x4 b) {
    f32x4 r;
    r.x = fmaxf(a.x, b.x); r.y = fmaxf(a.y, b.y);
    r.z = fmaxf(a.z, b.z); r.w = fmaxf(a.w, b.w);
    return r;
}
__device__ __forceinline__ f32x4 f4med3(f32x4 a, f32x4 b, f32x4 c) {
    f32x4 r;
    r.x = __builtin_amdgcn_fmed3f(a.x, b.x, c.x);
    r.y = __builtin_amdgcn_fmed3f(a.y, b.y, c.y);
    r.z = __builtin_amdgcn_fmed3f(a.z, b.z, c.z);
    r.w = __builtin_amdgcn_fmed3f(a.w, b.w, c.w);
    return r;
}

// Lower median of 5, 7 ops: min of pair-minima has rank<=2, max of
// pair-maxima has rank>=4 -> discard; med3 of survivors is the answer.
__device__ __forceinline__ f32x4 median5(f32x4 a, f32x4 b, f32x4 c,
                                         f32x4 d, f32x4 e) {
    f32x4 t1 = f4min(a, b), t2 = f4max(a, b);
    f32x4 t3 = f4min(c, d), t4 = f4max(c, d);
    f32x4 t5 = f4max(t1, t3);
    f32x4 t6 = f4min(t2, t4);
    return f4med3(t5, t6, e);
}

__global__ __launch_bounds__(256)
void MedianPool_73426760893099_kernel(const f32x4* __restrict__ x,
                                      f32x4* __restrict__ out) {
    // XCD-contiguous swizzle: nwg = 2048, divisible by 8.
    const int nwg  = gridDim.x;
    const int cpx  = nwg / NXCD;
    const int bid  = (int)blockIdx.x;
    const int bsw  = (bid % NXCD) * cpx + bid / NXCD;

    const int idx = bsw * blockDim.x + threadIdx.x;  // over B*LG*C4 = 524,288
    const int c4 = idx & (C4 - 1);
    const int lg = (idx >> 5) & (LG - 1);
    const int b  = idx >> 14;   // idx / (LG*C4)

    const f32x4* __restrict__ xb = x + (size_t)b * L * C4;
    const int l0 = lg * RPT;

    // Load RPT + 4 = 12 rows (circular).
    f32x4 r[RPT + 4];
#pragma unroll
    for (int i = 0; i < RPT + 4; ++i)
        r[i] = xb[(size_t)((l0 + i) & (L - 1)) * C4 + c4];

    f32x4* o = out + (size_t)b * L * C4 + (size_t)l0 * C4 + c4;
#pragma unroll
    for (int i = 0; i < RPT; ++i) {
        o[i * C4] = median5(r[i], r[i + 1], r[i + 2], r[i + 3], r[i + 4]);
    }
}

extern "C" void kernel_launch(void* const* d_in, const int* in_sizes, int n_in,
                              void* d_out, int out_size, void* d_ws, size_t ws_size,
                              hipStream_t stream) {
    const f32x4* x   = (const f32x4*)d_in[0];
    f32x4*       out = (f32x4*)d_out;

    const int threads = B * LG * C4;          // 524,288
    const int block   = 256;
    const int grid    = threads / block;      // 2048
    MedianPool_73426760893099_kernel<<<grid, block, 0, stream>>>(x, out);
}